// Round 15
// baseline (449.085 us; speedup 1.0000x reference)
//
#include <hip/hip_runtime.h>
#include <hip/hip_bf16.h>

constexpr int NPOINTS = 2 * 16384;        // B*N
constexpr int NSAMP   = NPOINTS * 16;     // B*N*K
constexpr int NSLOT   = 64;               // stats accumulator copies (contention striping)

// stats region layout (doubles), [NSLOT][nch] per group
constexpr int O_BN1S = 0,     O_BN1Q = 8192;    // 64*128
constexpr int O_FDS  = 16384, O_FDQ  = 16576;   // 64*3
constexpr int O_G1S  = 16768, O_G1Q  = 24960;
constexpr int O_G2S  = 33152, O_G2Q  = 34176;   // 64*16
constexpr int O_BN2S = 35200, O_BN2Q = 43392;
constexpr int O_BN3S = 51584, O_BN3Q = 59776;
constexpr int O_END  = 67968;

typedef __attribute__((ext_vector_type(8))) short short8;
typedef __attribute__((ext_vector_type(4))) short short4v;
typedef __attribute__((ext_vector_type(4))) float f32x4;

__device__ inline unsigned short f2bf(float x) {
    __hip_bfloat16 h = __float2bfloat16(x);
    unsigned short u;
    __builtin_memcpy(&u, &h, 2);
    return u;
}
__device__ inline float bf2f(unsigned short u) {
    return __uint_as_float(((unsigned)u) << 16);
}
__device__ inline float bflo(unsigned u) { return __uint_as_float(u << 16); }
__device__ inline float bfhi(unsigned u) { return __uint_as_float(u & 0xffff0000u); }
__device__ inline unsigned pack2bf(float lo, float hi) {
    float2 f; f.x = lo; f.y = hi;
    __hip_bfloat162 h = __float22bfloat162_rn(f);
    unsigned u; __builtin_memcpy(&u, &h, 4);
    return u;
}

// last-block BN finalize over NSLOT-striped partials
__device__ inline void bn_finalize_block(
    double* dsum, double* dsq, const float* g, const float* b,
    float* scale, float* shift, int nch, double cnt,
    unsigned int* ctr, unsigned int nblk, unsigned int* lastf)
{
    __syncthreads();
    if (threadIdx.x == 0) {
        __threadfence();
        *lastf = (atomicAdd(ctr, 1u) == nblk - 1u) ? 1u : 0u;
    }
    __syncthreads();
    if (*lastf) {
        __threadfence();
        for (int c = threadIdx.x; c < nch; c += blockDim.x) {
            double sm = 0.0, sq = 0.0;
            for (int s = 0; s < NSLOT; ++s) {
                sm += __hip_atomic_load(&dsum[s * nch + c], __ATOMIC_RELAXED, __HIP_MEMORY_SCOPE_AGENT);
                sq += __hip_atomic_load(&dsq[s * nch + c],  __ATOMIC_RELAXED, __HIP_MEMORY_SCOPE_AGENT);
            }
            double m = sm / cnt;
            double v = sq / cnt - m * m;
            double s2 = (double)g[c] / sqrt(v + 1e-5);
            scale[c] = (float)s2;
            shift[c] = (float)((double)b[c] - m * s2);
        }
    }
}

// XCD-pinned point enumeration
// 4-sweep variant (grid 2048): 16 pts/block
#define PIN_DECODE(x)  const int batch = ((x) >> 2) & 1; \
                       const int qb = (((x) >> 3) << 2) | ((x) & 3);
#define PIN_POINT4(s,w) ((batch << 14) + qb * 4 + (w) + ((s) << 12))
// 2-sweep variant (grid 4096): 8 pts/block
#define PIN_POINT2(s,w) ((batch << 14) + qb * 4 + (w) + ((s) << 13))

#define LOAD_IDX(idx, p) \
    int idx[16]; \
    { const int4* kp_ = (const int4*)(knn + (size_t)(p) * 16); \
      _Pragma("unroll") \
      for (int q_ = 0; q_ < 4; ++q_) { \
          int4 v_ = kp_[q_]; \
          idx[4*q_+0]=v_.x; idx[4*q_+1]=v_.y; idx[4*q_+2]=v_.z; idx[4*q_+3]=v_.w; } }

// ---------------------------------------------------------------- MFMA GEMM
// Out(bf16) = A @ W(128x128 f32->bf16) [+bias] [+bn stats+finalize]
// ASRC: 0=f32 plain; 1=bf16 plain; 2=f32 fused relu(fmaf); 3=bf16 fused relu(fmaf)
template<int ASRC, bool STATS, bool BIAS>
__global__ __launch_bounds__(256) void k_mgemm(
    const void* __restrict__ Ain, const float* __restrict__ W,
    const float* __restrict__ Bias, unsigned short* __restrict__ Out,
    const float* __restrict__ asc, const float* __restrict__ ash,
    double* __restrict__ dsum, double* __restrict__ dsq,
    const float* __restrict__ bng, const float* __restrict__ bnb,
    float* __restrict__ oscale, float* __restrict__ oshift,
    unsigned int* __restrict__ ctr, unsigned int nblk)
{
    __shared__ unsigned short bl[16384];   // W in fragment layout
    __shared__ unsigned int lastf;
    const int tid = threadIdx.x;
    for (int e = tid; e < 16384; e += 256) {
        int k = e >> 7, n = e & 127;
        int f = ((k >> 5) << 2) | ((k >> 3) & 3);
        int dst = f * 1024 + (n >> 4) * 128 + (n & 15) * 8 + (k & 7);
        bl[dst] = f2bf(W[e]);
    }
    __syncthreads();
    const int wid = tid >> 6, lane = tid & 63;
    const int l16 = lane & 15, g = lane >> 4;
    const long arow = (long)blockIdx.x * 64 + wid * 16 + l16;
    short8 afr[4];
    if constexpr (ASRC == 0) {
        const float* A = (const float*)Ain;
        #pragma unroll
        for (int kk = 0; kk < 4; ++kk) {
            const f32x4* src = reinterpret_cast<const f32x4*>(A + arow * 128 + kk * 32 + g * 8);
            f32x4 v0 = src[0], v1 = src[1];
            short8 v;
            #pragma unroll
            for (int i = 0; i < 4; ++i) { v[i] = (short)f2bf(v0[i]); v[4 + i] = (short)f2bf(v1[i]); }
            afr[kk] = v;
        }
    } else if constexpr (ASRC == 1) {
        const unsigned short* A = (const unsigned short*)Ain;
        #pragma unroll
        for (int kk = 0; kk < 4; ++kk)
            afr[kk] = *reinterpret_cast<const short8*>(A + arow * 128 + kk * 32 + g * 8);
    } else if constexpr (ASRC == 2) {
        const float* A = (const float*)Ain;
        #pragma unroll
        for (int kk = 0; kk < 4; ++kk) {
            const int ch0 = kk * 32 + g * 8;
            const f32x4* src = reinterpret_cast<const f32x4*>(A + arow * 128 + ch0);
            f32x4 v0 = src[0], v1 = src[1];
            short8 v;
            #pragma unroll
            for (int i = 0; i < 4; ++i) {
                v[i]     = (short)f2bf(fmaxf(fmaf(asc[ch0 + i],     v0[i], ash[ch0 + i]),     0.f));
                v[4 + i] = (short)f2bf(fmaxf(fmaf(asc[ch0 + 4 + i], v1[i], ash[ch0 + 4 + i]), 0.f));
            }
            afr[kk] = v;
        }
    } else {
        const unsigned short* A = (const unsigned short*)Ain;
        #pragma unroll
        for (int kk = 0; kk < 4; ++kk) {
            const int ch0 = kk * 32 + g * 8;
            short8 raw = *reinterpret_cast<const short8*>(A + arow * 128 + ch0);
            short8 v;
            #pragma unroll
            for (int i = 0; i < 8; ++i) {
                float x = fmaxf(fmaf(asc[ch0 + i], bf2f((unsigned short)raw[i]), ash[ch0 + i]), 0.f);
                v[i] = (short)f2bf(x);
            }
            afr[kk] = v;
        }
    }
    f32x4 acc[8];
    #pragma unroll
    for (int n = 0; n < 8; ++n) acc[n] = f32x4{0.f, 0.f, 0.f, 0.f};
    #pragma unroll
    for (int kk = 0; kk < 4; ++kk) {
        const int fb = (kk * 4 + g) * 1024 + l16 * 8;
        #pragma unroll
        for (int n = 0; n < 8; ++n) {
            short8 bf = *reinterpret_cast<const short8*>(&bl[fb + n * 128]);
            acc[n] = __builtin_amdgcn_mfma_f32_16x16x32_bf16(afr[kk], bf, acc[n], 0, 0, 0);
        }
    }
    const long orow0 = (long)blockIdx.x * 64 + wid * 16 + g * 4;
    float bia[8];
    if constexpr (BIAS) {
        #pragma unroll
        for (int n = 0; n < 8; ++n) bia[n] = Bias[n * 16 + l16];
    }
    float lsf[8], lqf[8];
    #pragma unroll
    for (int n = 0; n < 8; ++n) { lsf[n] = 0.f; lqf[n] = 0.f; }
    #pragma unroll
    for (int n = 0; n < 8; ++n) {
        #pragma unroll
        for (int r = 0; r < 4; ++r) {
            float v = acc[n][r];
            if constexpr (BIAS) v += bia[n];
            if constexpr (STATS) { lsf[n] += v; lqf[n] += v * v; }
            Out[(orow0 + r) * 128 + n * 16 + l16] = f2bf(v);
        }
    }
    if constexpr (STATS) {
        const int slot = blockIdx.x & (NSLOT - 1);
        #pragma unroll
        for (int n = 0; n < 8; ++n) {
            float s = lsf[n], q = lqf[n];
            s += __shfl_xor(s, 16); s += __shfl_xor(s, 32);
            q += __shfl_xor(q, 16); q += __shfl_xor(q, 32);
            if (g == 0) {
                atomicAdd(&dsum[slot * 128 + n * 16 + l16], (double)s);
                atomicAdd(&dsq[slot * 128 + n * 16 + l16], (double)q);
            }
        }
        bn_finalize_block(dsum, dsq, bng, bnb, oscale, oshift, 128, (double)NPOINTS, ctr, nblk, &lastf);
    }
}

// fused q/k/v: 3 GEMMs sharing one A pass; bn1+relu fused into A load.
__global__ __launch_bounds__(512) void k_qkv3(
    const unsigned short* __restrict__ Y,
    const float* __restrict__ sc, const float* __restrict__ sh,
    const float* __restrict__ Wq, const float* __restrict__ Bq,
    const float* __restrict__ Wk, const float* __restrict__ Bk,
    const float* __restrict__ Wv, const float* __restrict__ Bv,
    unsigned short* __restrict__ Qo, unsigned short* __restrict__ Ko,
    unsigned short* __restrict__ Vo)
{
    __shared__ unsigned short bl[3 * 16384];   // 96 KB
    const int tid = threadIdx.x;
    #pragma unroll
    for (int m = 0; m < 3; ++m) {
        const float* W = (m == 0) ? Wq : (m == 1) ? Wk : Wv;
        for (int e = tid; e < 16384; e += 512) {
            int k = e >> 7, n = e & 127;
            int f = ((k >> 5) << 2) | ((k >> 3) & 3);
            bl[m * 16384 + f * 1024 + (n >> 4) * 128 + (n & 15) * 8 + (k & 7)] = f2bf(W[e]);
        }
    }
    __syncthreads();
    const int wid = tid >> 6, lane = tid & 63;
    const int l16 = lane & 15, g = lane >> 4;
    const long arow = (long)blockIdx.x * 128 + wid * 16 + l16;
    short8 afr[4];
    #pragma unroll
    for (int kk = 0; kk < 4; ++kk) {
        const int ch0 = kk * 32 + g * 8;
        short8 raw = *reinterpret_cast<const short8*>(Y + arow * 128 + ch0);
        short8 v;
        #pragma unroll
        for (int i = 0; i < 8; ++i) {
            float x = fmaxf(fmaf(sc[ch0 + i], bf2f((unsigned short)raw[i]), sh[ch0 + i]), 0.f);
            v[i] = (short)f2bf(x);
        }
        afr[kk] = v;
    }
    const long orow0 = (long)blockIdx.x * 128 + wid * 16 + g * 4;
    #pragma unroll
    for (int m = 0; m < 3; ++m) {
        const float* Bias = (m == 0) ? Bq : (m == 1) ? Bk : Bv;
        unsigned short* Out = (m == 0) ? Qo : (m == 1) ? Ko : Vo;
        f32x4 acc[8];
        #pragma unroll
        for (int n = 0; n < 8; ++n) acc[n] = f32x4{0.f, 0.f, 0.f, 0.f};
        #pragma unroll
        for (int kk = 0; kk < 4; ++kk) {
            const int fb = m * 16384 + (kk * 4 + g) * 1024 + l16 * 8;
            #pragma unroll
            for (int n = 0; n < 8; ++n) {
                short8 bf = *reinterpret_cast<const short8*>(&bl[fb + n * 128]);
                acc[n] = __builtin_amdgcn_mfma_f32_16x16x32_bf16(afr[kk], bf, acc[n], 0, 0, 0);
            }
        }
        #pragma unroll
        for (int n = 0; n < 8; ++n) {
            const float bia = Bias[n * 16 + l16];
            #pragma unroll
            for (int r = 0; r < 4; ++r)
                Out[(orow0 + r) * 128 + n * 16 + l16] = f2bf(acc[n][r] + bia);
        }
    }
}

// stats of h = rel @ fd_w1 + fd_b1 over (B,N,K), 3 channels (+finalize)
__global__ __launch_bounds__(256) void k_fd_stats(
    const float* __restrict__ xyz, const int* __restrict__ knn,
    const float* __restrict__ fdw1, const float* __restrict__ fdb1,
    double* __restrict__ dsum, double* __restrict__ dsq,
    const float* __restrict__ bng, const float* __restrict__ bnb,
    float* __restrict__ oscale, float* __restrict__ oshift,
    unsigned int* __restrict__ ctr, unsigned int nblk)
{
    __shared__ unsigned int lastf;
    float wd[9], bd[3];
    #pragma unroll
    for (int i = 0; i < 9; ++i) wd[i] = fdw1[i];
    #pragma unroll
    for (int j = 0; j < 3; ++j) bd[j] = fdb1[j];
    double ls[3] = {0, 0, 0}, lq[3] = {0, 0, 0};
    for (int s = blockIdx.x * blockDim.x + threadIdx.x; s < NSAMP; s += gridDim.x * blockDim.x) {
        int p = s >> 4;
        int b = p >> 14, n = p & 16383;
        int idx = knn[s];
        const float* pa = xyz + (b * 16384 + n) * 3;
        const float* pb = xyz + (b * 16384 + idx) * 3;
        float r0 = pa[0] - pb[0], r1 = pa[1] - pb[1], r2 = pa[2] - pb[2];
        #pragma unroll
        for (int j = 0; j < 3; ++j) {
            float h = r0 * wd[j] + r1 * wd[3 + j] + r2 * wd[6 + j] + bd[j];
            ls[j] += h; lq[j] += (double)h * h;
        }
    }
    const int slot = blockIdx.x & (NSLOT - 1);
    #pragma unroll
    for (int j = 0; j < 3; ++j) {
        double v = ls[j];
        for (int o = 32; o; o >>= 1) v += __shfl_down(v, o);
        if ((threadIdx.x & 63) == 0) atomicAdd(&dsum[slot * 3 + j], v);
        v = lq[j];
        for (int o = 32; o; o >>= 1) v += __shfl_down(v, o);
        if ((threadIdx.x & 63) == 0) atomicAdd(&dsq[slot * 3 + j], v);
    }
    bn_finalize_block(dsum, dsq, bng, bnb, oscale, oshift, 3, (double)NSAMP, ctr, nblk, &lastf);
}

// stats of attn0 = q - k_gather + pos_enc, 128 ch (+finalize). Slim LDS, grid 4096x2.
__global__ __launch_bounds__(256) void k_attn1_stats(
    const unsigned short* __restrict__ Q, const unsigned short* __restrict__ Kb,
    const float* __restrict__ xyz, const int* __restrict__ knn,
    const float* __restrict__ fdw1, const float* __restrict__ fdb1,
    const float* __restrict__ fds, const float* __restrict__ fdh,
    const float* __restrict__ fdw2, const float* __restrict__ fdb2,
    double* __restrict__ dsum, double* __restrict__ dsq,
    const float* __restrict__ bng, const float* __restrict__ bnb,
    float* __restrict__ oscale, float* __restrict__ oshift,
    unsigned int* __restrict__ ctr, unsigned int nblk)
{
    __shared__ float pe3_all[4][16][4];
    __shared__ float red[1024];
    __shared__ unsigned int lastf;
    const int tid = threadIdx.x, w = tid >> 6, l = tid & 63;
    float (*pe3)[4] = pe3_all[w];
    const int c0 = 2 * l;
    const float w0a = fdw2[c0],       w0b = fdw2[c0 + 1];
    const float w1a = fdw2[128 + c0], w1b = fdw2[129 + c0];
    const float w2a = fdw2[256 + c0], w2b = fdw2[257 + c0];
    const float bba = fdb2[c0],       bbb = fdb2[c0 + 1];
    float wd[9], bd[3], fs3[3], fh3[3];
    #pragma unroll
    for (int i = 0; i < 9; ++i) wd[i] = fdw1[i];
    #pragma unroll
    for (int j = 0; j < 3; ++j) { bd[j] = fdb1[j]; fs3[j] = fds[j]; fh3[j] = fdh[j]; }
    PIN_DECODE(blockIdx.x);
    const unsigned* kb32 = (const unsigned*)(Kb + (((size_t)batch) << 14) * 128);
    float ls0 = 0.f, lq0 = 0.f, ls1 = 0.f, lq1 = 0.f;
    for (int s = 0; s < 2; ++s) {
        const int p = PIN_POINT2(s, w);
        LOAD_IDX(idx, p);
        if (l < 16) {
            const int mi = knn[p * 16 + l];
            const int n = p & 16383;
            const float* pa = xyz + (batch * 16384 + n) * 3;
            const float* pb = xyz + (batch * 16384 + mi) * 3;
            const float r0 = pa[0] - pb[0], r1 = pa[1] - pb[1], r2 = pa[2] - pb[2];
            #pragma unroll
            for (int j = 0; j < 3; ++j) {
                float h = r0 * wd[j] + r1 * wd[3 + j] + r2 * wd[6 + j] + bd[j];
                pe3[l][j] = fmaxf(fmaf(fs3[j], h, fh3[j]), 0.f);
            }
        }
        unsigned kw[16];
        #pragma unroll
        for (int kk = 0; kk < 16; ++kk) kw[kk] = kb32[idx[kk] * 64 + l];
        const unsigned qw = ((const unsigned*)(Q + (size_t)p * 128))[l];
        const float qa = bflo(qw), qb = bfhi(qw);
        float pls0 = 0.f, plq0 = 0.f, pls1 = 0.f, plq1 = 0.f;
        #pragma unroll
        for (int kk = 0; kk < 16; ++kk) {
            const float pea = fmaf(pe3[kk][0], w0a, fmaf(pe3[kk][1], w1a, fmaf(pe3[kk][2], w2a, bba)));
            const float peb = fmaf(pe3[kk][0], w0b, fmaf(pe3[kk][1], w1b, fmaf(pe3[kk][2], w2b, bbb)));
            const float a0 = qa - bflo(kw[kk]) + pea;
            const float a1 = qb - bfhi(kw[kk]) + peb;
            pls0 += a0; plq0 = fmaf(a0, a0, plq0);
            pls1 += a1; plq1 = fmaf(a1, a1, plq1);
        }
        ls0 += pls0; lq0 += plq0; ls1 += pls1; lq1 += plq1;
    }
    __syncthreads();
    red[tid] = ls0; red[256 + tid] = ls1; red[512 + tid] = lq0; red[768 + tid] = lq1;
    __syncthreads();
    if (w == 0) {
        const int slot = blockIdx.x & (NSLOT - 1);
        const double s0 = (double)red[l] + red[64 + l] + red[128 + l] + red[192 + l];
        const double s1 = (double)red[256 + l] + red[320 + l] + red[384 + l] + red[448 + l];
        const double q0 = (double)red[512 + l] + red[576 + l] + red[640 + l] + red[704 + l];
        const double q1 = (double)red[768 + l] + red[832 + l] + red[896 + l] + red[960 + l];
        atomicAdd(&dsum[slot * 128 + c0], s0); atomicAdd(&dsum[slot * 128 + c0 + 1], s1);
        atomicAdd(&dsq[slot * 128 + c0], q0); atomicAdd(&dsq[slot * 128 + c0 + 1], q1);
    }
    bn_finalize_block(dsum, dsq, bng, bnb, oscale, oshift, 128, (double)NSAMP, ctr, nblk, &lastf);
}

// stats of t = relu(bn(attn0)) @ fg_w1 + fg_b1, 16 ch (+finalize); stores t bf16.
// UNCHANGED from r12 config (grid 2048x4) — s1b MFMA tile keeps LDS at 17 KB.
__global__ __launch_bounds__(256) void k_attn2_stats(
    const unsigned short* __restrict__ Q, const unsigned short* __restrict__ Kb,
    const float* __restrict__ xyz, const int* __restrict__ knn,
    const float* __restrict__ fdw1, const float* __restrict__ fdb1,
    const float* __restrict__ fds, const float* __restrict__ fdh,
    const float* __restrict__ fdw2, const float* __restrict__ fdb2,
    const float* __restrict__ g1s, const float* __restrict__ g1h,
    const float* __restrict__ fgw1, const float* __restrict__ fgb1,
    unsigned short* __restrict__ Tb,
    double* __restrict__ dsum, double* __restrict__ dsq,
    const float* __restrict__ bng, const float* __restrict__ bnb,
    float* __restrict__ oscale, float* __restrict__ oshift,
    unsigned int* __restrict__ ctr, unsigned int nblk)
{
    __shared__ __align__(16) unsigned short s1b_all[4][2048];
    __shared__ float pe3_all[4][16][4];
    __shared__ unsigned int lastf;
    const int tid = threadIdx.x, w = tid >> 6, l = tid & 63;
    unsigned short* s1b = s1b_all[w];
    float (*pe3)[4] = pe3_all[w];
    const int c0 = 2 * l;
    const int a16 = l & 15, g8 = (l >> 4) * 8;
    const float w0a = fdw2[c0],       w0b = fdw2[c0 + 1];
    const float w1a = fdw2[128 + c0], w1b = fdw2[129 + c0];
    const float w2a = fdw2[256 + c0], w2b = fdw2[257 + c0];
    const float bba = fdb2[c0],       bbb = fdb2[c0 + 1];
    const float sA = g1s[c0], hA = g1h[c0];
    const float sB = g1s[c0 + 1], hB = g1h[c0 + 1];
    const float tb = fgb1[a16];
    float wd[9], bd[3], fs3[3], fh3[3];
    #pragma unroll
    for (int i = 0; i < 9; ++i) wd[i] = fdw1[i];
    #pragma unroll
    for (int j = 0; j < 3; ++j) { bd[j] = fdb1[j]; fs3[j] = fds[j]; fh3[j] = fdh[j]; }
    short8 bfrag[4];
    #pragma unroll
    for (int s = 0; s < 4; ++s)
        #pragma unroll
        for (int i = 0; i < 8; ++i)
            bfrag[s][i] = (short)f2bf(fgw1[(32 * s + g8 + i) * 16 + a16]);
    PIN_DECODE(blockIdx.x);
    const unsigned* kb32 = (const unsigned*)(Kb + (((size_t)batch) << 14) * 128);
    double ls = 0.0, lq = 0.0;
    for (int s = 0; s < 4; ++s) {
        const int p = PIN_POINT4(s, w);
        LOAD_IDX(idx, p);
        if (l < 16) {
            const int mi = knn[p * 16 + l];
            const int n = p & 16383;
            const float* pa = xyz + (batch * 16384 + n) * 3;
            const float* pb = xyz + (batch * 16384 + mi) * 3;
            const float r0 = pa[0] - pb[0], r1 = pa[1] - pb[1], r2 = pa[2] - pb[2];
            #pragma unroll
            for (int j = 0; j < 3; ++j) {
                float h = r0 * wd[j] + r1 * wd[3 + j] + r2 * wd[6 + j] + bd[j];
                pe3[l][j] = fmaxf(fmaf(fs3[j], h, fh3[j]), 0.f);
            }
        }
        unsigned kw[16];
        #pragma unroll
        for (int kk = 0; kk < 16; ++kk) kw[kk] = kb32[idx[kk] * 64 + l];
        const unsigned qw = ((const unsigned*)(Q + (size_t)p * 128))[l];
        const float qa = bflo(qw), qb = bfhi(qw);
        #pragma unroll
        for (int kk = 0; kk < 16; ++kk) {
            const float pea = fmaf(pe3[kk][0], w0a, fmaf(pe3[kk][1], w1a, fmaf(pe3[kk][2], w2a, bba)));
            const float peb = fmaf(pe3[kk][0], w0b, fmaf(pe3[kk][1], w1b, fmaf(pe3[kk][2], w2b, bbb)));
            const float a0 = qa - bflo(kw[kk]) + pea;
            const float a1 = qb - bfhi(kw[kk]) + peb;
            const float v0 = fmaxf(fmaf(sA, a0, hA), 0.f);
            const float v1 = fmaxf(fmaf(sB, a1, hB), 0.f);
            ((unsigned*)s1b)[(((kk * 128 + c0) ^ ((kk & 7) << 3)) >> 1)] = pack2bf(v0, v1);
        }
        f32x4 acc = {0.f, 0.f, 0.f, 0.f};
        #pragma unroll
        for (int ss = 0; ss < 4; ++ss) {
            const int ai = (a16 * 128 + ss * 32 + g8) ^ ((a16 & 7) << 3);
            short8 af = *reinterpret_cast<const short8*>(&s1b[ai]);
            acc = __builtin_amdgcn_mfma_f32_16x16x32_bf16(af, bfrag[ss], acc, 0, 0, 0);
        }
        short4v tq;
        float pls = 0.f, plq = 0.f;
        #pragma unroll
        for (int r = 0; r < 4; ++r) {
            const float t = acc[r] + tb;
            tq[r] = (short)f2bf(t);
            pls += t; plq = fmaf(t, t, plq);
        }
        *reinterpret_cast<short4v*>(Tb + (size_t)p * 256 + l * 4) = tq;
        ls += pls; lq += plq;
    }
    __syncthreads();   // all waves done with s1b before red aliases it
    double* red = (double*)&s1b_all[0][0];
    red[tid] = ls; red[256 + tid] = lq;
    __syncthreads();
    if (tid < 16) {
        const int slot = blockIdx.x & (NSLOT - 1);
        double s = 0.0, q = 0.0;
        for (int i = 0; i < 16; ++i) { s += red[tid + 16 * i]; q += red[256 + tid + 16 * i]; }
        atomicAdd(&dsum[slot * 16 + tid], s); atomicAdd(&dsq[slot * 16 + tid], q);
    }
    bn_finalize_block(dsum, dsq, bng, bnb, oscale, oshift, 16, (double)NSAMP, ctr, nblk, &lastf);
}

// final attention from stored t: bn2 -> stage2 -> softmax -> PV ; bn2 stats. RES bf16.
// Slim LDS (red f32 aliases t2l region), grid 4096x2.
__global__ __launch_bounds__(256) void k_attn_final(
    const unsigned short* __restrict__ Tb, const unsigned short* __restrict__ Vb,
    const float* __restrict__ xyz, const int* __restrict__ knn,
    const float* __restrict__ fdw1, const float* __restrict__ fdb1,
    const float* __restrict__ fds, const float* __restrict__ fdh,
    const float* __restrict__ fdw2, const float* __restrict__ fdb2,
    const float* __restrict__ g2s, const float* __restrict__ g2h,
    const float* __restrict__ fgw2, const float* __restrict__ fgb2,
    unsigned short* __restrict__ Res, double* __restrict__ dsum, double* __restrict__ dsq,
    const float* __restrict__ bng, const float* __restrict__ bnb,
    float* __restrict__ oscale, float* __restrict__ oshift,
    unsigned int* __restrict__ ctr, unsigned int nblk)
{
    __shared__ float t2l_all[4][272];
    __shared__ float wl_all[4][272];
    __shared__ float pe3_all[4][16][4];
    __shared__ unsigned int lastf;
    const int tid = threadIdx.x, w = tid >> 6, l = tid & 63;
    float* t2l = t2l_all[w];
    float* wl  = wl_all[w];
    float (*pe3)[4] = pe3_all[w];
    const int c0 = 2 * l;
    const int a16 = l & 15, g4 = l >> 4;
    const int aA = c0 & 15;
    const float w0a = fdw2[c0],       w0b = fdw2[c0 + 1];
    const float w1a = fdw2[128 + c0], w1b = fdw2[129 + c0];
    const float w2a = fdw2[256 + c0], w2b = fdw2[257 + c0];
    const float bba = fdb2[c0],       bbb = fdb2[c0 + 1];
    const float s2a = g2s[a16], s2h = g2h[a16], b2a = fgb2[a16];
    float wd[9], bd[3], fs3[3], fh3[3];
    #pragma unroll
    for (int i = 0; i < 9; ++i) wd[i] = fdw1[i];
    #pragma unroll
    for (int j = 0; j < 3; ++j) { bd[j] = fdb1[j]; fs3[j] = fds[j]; fh3[j] = fdh[j]; }
    float wv2[16];
    #pragma unroll
    for (int j = 0; j < 16; ++j) wv2[j] = fgw2[j * 16 + a16];
    PIN_DECODE(blockIdx.x);
    const unsigned* vb32 = (const unsigned*)(Vb + (((size_t)batch) << 14) * 128);
    float lsA = 0.f, lqA = 0.f, lsB = 0.f, lqB = 0.f;
    for (int s = 0; s < 2; ++s) {
        const int p = PIN_POINT2(s, w);
        LOAD_IDX(idx, p);
        unsigned vw[16];
        #pragma unroll
        for (int kk = 0; kk < 16; ++kk) vw[kk] = vb32[idx[kk] * 64 + l];
        if (l < 16) {
            const int mi = knn[p * 16 + l];
            const int n = p & 16383;
            const float* pa = xyz + (batch * 16384 + n) * 3;
            const float* pb = xyz + (batch * 16384 + mi) * 3;
            const float r0 = pa[0] - pb[0], r1 = pa[1] - pb[1], r2 = pa[2] - pb[2];
            #pragma unroll
            for (int j = 0; j < 3; ++j) {
                float h = r0 * wd[j] + r1 * wd[3 + j] + r2 * wd[6 + j] + bd[j];
                pe3[l][j] = fmaxf(fmaf(fs3[j], h, fh3[j]), 0.f);
            }
        }
        short4v tv = *reinterpret_cast<const short4v*>(Tb + (size_t)p * 256 + l * 4);
        #pragma unroll
        for (int r = 0; r < 4; ++r)
            t2l[(g4 * 4 + r) * 17 + a16] = fmaxf(fmaf(s2a, bf2f((unsigned short)tv[r]), s2h), 0.f);
        float ur[4];
        #pragma unroll
        for (int r = 0; r < 4; ++r) {
            float u = b2a;
            #pragma unroll
            for (int j = 0; j < 16; ++j) u = fmaf(t2l[(g4 * 4 + r) * 17 + j], wv2[j], u);
            ur[r] = u;
        }
        float m = fmaxf(fmaxf(ur[0], ur[1]), fmaxf(ur[2], ur[3]));
        m = fmaxf(m, __shfl_xor(m, 16));
        m = fmaxf(m, __shfl_xor(m, 32));
        const float e0 = __expf(ur[0] - m), e1 = __expf(ur[1] - m);
        const float e2 = __expf(ur[2] - m), e3 = __expf(ur[3] - m);
        float ss = e0 + e1 + e2 + e3;
        ss += __shfl_xor(ss, 16);
        ss += __shfl_xor(ss, 32);
        const float inv = 1.f / ss;
        wl[(g4 * 4 + 0) * 17 + a16] = e0 * inv;
        wl[(g4 * 4 + 1) * 17 + a16] = e1 * inv;
        wl[(g4 * 4 + 2) * 17 + a16] = e2 * inv;
        wl[(g4 * 4 + 3) * 17 + a16] = e3 * inv;
        float rc0 = 0.f, rc1 = 0.f;
        #pragma unroll
        for (int kk = 0; kk < 16; ++kk) {
            const float wgtA = wl[kk * 17 + aA];
            const float wgtB = wl[kk * 17 + aA + 1];
            const float pea = fmaf(pe3[kk][0], w0a, fmaf(pe3[kk][1], w1a, fmaf(pe3[kk][2], w2a, bba)));
            const float peb = fmaf(pe3[kk][0], w0b, fmaf(pe3[kk][1], w1b, fmaf(pe3[kk][2], w2b, bbb)));
            rc0 = fmaf(bflo(vw[kk]) + pea, wgtA, rc0);
            rc1 = fmaf(bfhi(vw[kk]) + peb, wgtB, rc1);
        }
        ((unsigned*)Res)[(size_t)p * 64 + l] = pack2bf(rc0, rc1);
        lsA += rc0; lqA = fmaf(rc0, rc0, lqA);
        lsB += rc1; lqB = fmaf(rc1, rc1, lqB);
    }
    // red (f32[1024]) aliases t2l_all (1088 floats) — all waves done with t2l/wl
    __syncthreads();
    float* red = (float*)&t2l_all[0][0];
    red[tid] = lsA; red[256 + tid] = lsB; red[512 + tid] = lqA; red[768 + tid] = lqB;
    __syncthreads();
    if (w == 0) {
        const int slot = blockIdx.x & (NSLOT - 1);
        const double s0 = (double)red[l] + red[64 + l] + red[128 + l] + red[192 + l];
        const double s1 = (double)red[256 + l] + red[320 + l] + red[384 + l] + red[448 + l];
        const double q0 = (double)red[512 + l] + red[576 + l] + red[640 + l] + red[704 + l];
        const double q1 = (double)red[768 + l] + red[832 + l] + red[896 + l] + red[960 + l];
        atomicAdd(&dsum[slot * 128 + c0], s0); atomicAdd(&dsum[slot * 128 + c0 + 1], s1);
        atomicAdd(&dsq[slot * 128 + c0], q0); atomicAdd(&dsq[slot * 128 + c0 + 1], q1);
    }
    bn_finalize_block(dsum, dsq, bng, bnb, oscale, oshift, 128, (double)NPOINTS, ctr, nblk, &lastf);
}

// out = relu(bn3(y3) + identity); tail blocks copy xyz -> out[0:98304)
__global__ __launch_bounds__(256) void k_out(
    const unsigned short* __restrict__ Y3, const float* __restrict__ sc,
    const float* __restrict__ sh, const float* __restrict__ feat,
    const float* __restrict__ xyz, float* __restrict__ out)
{
    if (blockIdx.x < 2048) {
        const int v = blockIdx.x * 256 + threadIdx.x;
        const int base = v * 8;
        short8 y = *reinterpret_cast<const short8*>(&Y3[base]);
        const int c0 = base & 127;
        float* o = out + 98304;
        #pragma unroll
        for (int j = 0; j < 8; ++j) {
            float val = fmaf(sc[c0 + j], bf2f((unsigned short)y[j]), sh[c0 + j]) + feat[base + j];
            o[base + j] = fmaxf(val, 0.f);
        }
    } else {
        const int v = (blockIdx.x - 2048) * 256 + threadIdx.x;
        const int base = v * 8;     // 48 blocks * 256 thr * 8 = 98304
        const f32x4* src = reinterpret_cast<const f32x4*>(xyz + base);
        f32x4* dst = reinterpret_cast<f32x4*>(out + base);
        dst[0] = src[0];
        dst[1] = src[1];
    }
}

extern "C" void kernel_launch(void* const* d_in, const int* in_sizes, int n_in,
                              void* d_out, int out_size, void* d_ws, size_t ws_size,
                              hipStream_t stream)
{
    (void)in_sizes; (void)n_in; (void)out_size; (void)ws_size;
    const float* xyz   = (const float*)d_in[0];
    const float* feat  = (const float*)d_in[1];
    const int*   knn   = (const int*)d_in[2];
    const float* w1    = (const float*)d_in[3];
    const float* bn1g  = (const float*)d_in[4];
    const float* bn1b  = (const float*)d_in[5];
    const float* lqw   = (const float*)d_in[6];
    const float* lqb   = (const float*)d_in[7];
    const float* lkw   = (const float*)d_in[8];
    const float* lkb   = (const float*)d_in[9];
    const float* lvw   = (const float*)d_in[10];
    const float* lvb   = (const float*)d_in[11];
    const float* fdw1  = (const float*)d_in[12];
    const float* fdb1  = (const float*)d_in[13];
    const float* fdbng = (const float*)d_in[14];
    const float* fdbnb = (const float*)d_in[15];
    const float* fdw2  = (const float*)d_in[16];
    const float* fdb2  = (const float*)d_in[17];
    const float* g1g   = (const float*)d_in[18];
    const float* g1b   = (const float*)d_in[19];
    const float* fgw1  = (const float*)d_in[20];
    const float* fgb1  = (const float*)d_in[21];
    const float* g2g   = (const float*)d_in[22];
    const float* g2b   = (const float*)d_in[23];
    const float* fgw2  = (const float*)d_in[24];
    const float* fgb2  = (const float*)d_in[25];
    const float* bn2g  = (const float*)d_in[26];
    const float* bn2b  = (const float*)d_in[27];
    const float* w3    = (const float*)d_in[28];
    const float* bn3g  = (const float*)d_in[29];
    const float* bn3b  = (const float*)d_in[30];

    unsigned short* YBF = (unsigned short*)d_ws;            // bf16 y   [0,8M)
    unsigned short* RES = YBF;                              // bf16 res overlays y [0,8M)
    unsigned short* Qb  = YBF + 2 * 4194304;                // [16M,24M)
    unsigned short* Kb  = Qb + 4194304;                     // [24M,32M)
    unsigned short* Vb  = Kb + 4194304;                     // [32M,40M)
    unsigned short* Tb  = Vb + 4194304;                     // [40M,56M) stored t (bf16)
    unsigned short* Y3  = Qb;                               // overlays Q
    double* ds = (double*)(Tb + 8388608);
    unsigned int* ctrs = (unsigned int*)(ds + O_END);       // 6 counters
    float* fs = (float*)(ds + O_END + 8);

    hipMemsetAsync(ds, 0, (size_t)(O_END + 8) * sizeof(double), stream);

    // bn1 over feat@w1 (stats+finalize folded)
    k_mgemm<0, true, false><<<512, 256, 0, stream>>>(feat, w1, nullptr, YBF, nullptr, nullptr,
                                                     ds + O_BN1S, ds + O_BN1Q,
                                                     bn1g, bn1b, fs + 0, fs + 128, ctrs + 0, 512u);
    // fused q,k,v projections (bn1+relu folded into A load)
    k_qkv3<<<256, 512, 0, stream>>>(YBF, fs + 0, fs + 128, lqw, lqb, lkw, lkb, lvw, lvb, Qb, Kb, Vb);
    // fd BN stats (3ch)
    k_fd_stats<<<256, 256, 0, stream>>>(xyz, knn, fdw1, fdb1, ds + O_FDS, ds + O_FDQ,
                                        fdbng, fdbnb, fs + 256, fs + 264, ctrs + 1, 256u);
    // fg_bn1 stats (128ch) — slim LDS, grid 4096x2
    k_attn1_stats<<<4096, 256, 0, stream>>>(Qb, Kb, xyz, knn, fdw1, fdb1, fs + 256, fs + 264,
                                            fdw2, fdb2, ds + O_G1S, ds + O_G1Q,
                                            g1g, g1b, fs + 272, fs + 400, ctrs + 2, 4096u);
    // fg_bn2 stats (16ch) + store t — unchanged (grid 2048x4)
    k_attn2_stats<<<2048, 256, 0, stream>>>(Qb, Kb, xyz, knn, fdw1, fdb1, fs + 256, fs + 264,
                                            fdw2, fdb2, fs + 272, fs + 400, fgw1, fgb1, Tb,
                                            ds + O_G2S, ds + O_G2Q,
                                            g2g, g2b, fs + 528, fs + 544, ctrs + 3, 2048u);
    // final attention from stored t -> RES (bf16), bn2 stats — slim LDS, grid 4096x2
    k_attn_final<<<4096, 256, 0, stream>>>(Tb, Vb, xyz, knn, fdw1, fdb1, fs + 256, fs + 264,
                                           fdw2, fdb2, fs + 528, fs + 544, fgw2, fgb2,
                                           RES, ds + O_BN2S, ds + O_BN2Q,
                                           bn2g, bn2b, fs + 560, fs + 688, ctrs + 4, 4096u);
    // y3 = relu(bn2(res)) @ w3 (bn2+relu folded, bf16 A), bn3 stats
    k_mgemm<3, true, false><<<512, 256, 0, stream>>>(RES, w3, nullptr, Y3, fs + 560, fs + 688,
                                                     ds + O_BN3S, ds + O_BN3Q,
                                                     bn3g, bn3b, fs + 816, fs + 944, ctrs + 5, 512u);
    // output (+ xyz copy in tail blocks)
    float* outp = (float*)d_out;
    k_out<<<2096, 256, 0, stream>>>(Y3, fs + 816, fs + 944, feat, xyz, outp);
}

// Round 16
// 351.172 us; speedup vs baseline: 1.2788x; 1.2788x over previous
//
#include <hip/hip_runtime.h>
#include <hip/hip_bf16.h>

constexpr int NPOINTS = 2 * 16384;        // B*N
constexpr int NSAMP   = NPOINTS * 16;     // B*N*K
constexpr int NSLOT   = 64;               // stats accumulator copies (contention striping)

// stats region layout (doubles), [NSLOT][nch] per group
constexpr int O_BN1S = 0,     O_BN1Q = 8192;    // 64*128
constexpr int O_FDS  = 16384, O_FDQ  = 16576;   // 64*3
constexpr int O_G1S  = 16768, O_G1Q  = 24960;
constexpr int O_G2S  = 33152, O_G2Q  = 34176;   // 64*16
constexpr int O_BN2S = 35200, O_BN2Q = 43392;
constexpr int O_BN3S = 51584, O_BN3Q = 59776;
constexpr int O_END  = 67968;

typedef __attribute__((ext_vector_type(8))) short short8;
typedef __attribute__((ext_vector_type(4))) short short4v;
typedef __attribute__((ext_vector_type(4))) float f32x4;

__device__ inline unsigned short f2bf(float x) {
    __hip_bfloat16 h = __float2bfloat16(x);
    unsigned short u;
    __builtin_memcpy(&u, &h, 2);
    return u;
}
__device__ inline float bf2f(unsigned short u) {
    return __uint_as_float(((unsigned)u) << 16);
}
__device__ inline float bflo(unsigned u) { return __uint_as_float(u << 16); }
__device__ inline float bfhi(unsigned u) { return __uint_as_float(u & 0xffff0000u); }
__device__ inline unsigned pack2bf(float lo, float hi) {
    float2 f; f.x = lo; f.y = hi;
    __hip_bfloat162 h = __float22bfloat162_rn(f);
    unsigned u; __builtin_memcpy(&u, &h, 4);
    return u;
}

// last-block BN finalize over NSLOT-striped partials
__device__ inline void bn_finalize_block(
    double* dsum, double* dsq, const float* g, const float* b,
    float* scale, float* shift, int nch, double cnt,
    unsigned int* ctr, unsigned int nblk, unsigned int* lastf)
{
    __syncthreads();
    if (threadIdx.x == 0) {
        __threadfence();
        *lastf = (atomicAdd(ctr, 1u) == nblk - 1u) ? 1u : 0u;
    }
    __syncthreads();
    if (*lastf) {
        __threadfence();
        for (int c = threadIdx.x; c < nch; c += blockDim.x) {
            double sm = 0.0, sq = 0.0;
            for (int s = 0; s < NSLOT; ++s) {
                sm += __hip_atomic_load(&dsum[s * nch + c], __ATOMIC_RELAXED, __HIP_MEMORY_SCOPE_AGENT);
                sq += __hip_atomic_load(&dsq[s * nch + c],  __ATOMIC_RELAXED, __HIP_MEMORY_SCOPE_AGENT);
            }
            double m = sm / cnt;
            double v = sq / cnt - m * m;
            double s2 = (double)g[c] / sqrt(v + 1e-5);
            scale[c] = (float)s2;
            shift[c] = (float)((double)b[c] - m * s2);
        }
    }
}

// XCD-pinned point enumeration (grid 2048, 4 waves, 4 sweeps -> 16 pts/block)
#define PIN_DECODE(x)  const int batch = ((x) >> 2) & 1; \
                       const int qb = (((x) >> 3) << 2) | ((x) & 3);
#define PIN_POINT(s,w) ((batch << 14) + qb * 4 + (w) + ((s) << 12))

#define LOAD_IDX(idx, p) \
    int idx[16]; \
    { const int4* kp_ = (const int4*)(knn + (size_t)(p) * 16); \
      _Pragma("unroll") \
      for (int q_ = 0; q_ < 4; ++q_) { \
          int4 v_ = kp_[q_]; \
          idx[4*q_+0]=v_.x; idx[4*q_+1]=v_.y; idx[4*q_+2]=v_.z; idx[4*q_+3]=v_.w; } }

// ---------------------------------------------------------------- MFMA GEMM
// Out(bf16) = A @ W(128x128 f32->bf16) [+bias] [+bn stats+finalize]
// ASRC: 0=f32 plain; 1=bf16 plain; 2=f32 fused relu(fmaf); 3=bf16 fused relu(fmaf)
template<int ASRC, bool STATS, bool BIAS>
__global__ __launch_bounds__(256) void k_mgemm(
    const void* __restrict__ Ain, const float* __restrict__ W,
    const float* __restrict__ Bias, unsigned short* __restrict__ Out,
    const float* __restrict__ asc, const float* __restrict__ ash,
    double* __restrict__ dsum, double* __restrict__ dsq,
    const float* __restrict__ bng, const float* __restrict__ bnb,
    float* __restrict__ oscale, float* __restrict__ oshift,
    unsigned int* __restrict__ ctr, unsigned int nblk)
{
    __shared__ unsigned short bl[16384];   // W in fragment layout
    __shared__ unsigned int lastf;
    const int tid = threadIdx.x;
    for (int e = tid; e < 16384; e += 256) {
        int k = e >> 7, n = e & 127;
        int f = ((k >> 5) << 2) | ((k >> 3) & 3);
        int dst = f * 1024 + (n >> 4) * 128 + (n & 15) * 8 + (k & 7);
        bl[dst] = f2bf(W[e]);
    }
    __syncthreads();
    const int wid = tid >> 6, lane = tid & 63;
    const int l16 = lane & 15, g = lane >> 4;
    const long arow = (long)blockIdx.x * 64 + wid * 16 + l16;
    short8 afr[4];
    if constexpr (ASRC == 0) {
        const float* A = (const float*)Ain;
        #pragma unroll
        for (int kk = 0; kk < 4; ++kk) {
            const f32x4* src = reinterpret_cast<const f32x4*>(A + arow * 128 + kk * 32 + g * 8);
            f32x4 v0 = src[0], v1 = src[1];
            short8 v;
            #pragma unroll
            for (int i = 0; i < 4; ++i) { v[i] = (short)f2bf(v0[i]); v[4 + i] = (short)f2bf(v1[i]); }
            afr[kk] = v;
        }
    } else if constexpr (ASRC == 1) {
        const unsigned short* A = (const unsigned short*)Ain;
        #pragma unroll
        for (int kk = 0; kk < 4; ++kk)
            afr[kk] = *reinterpret_cast<const short8*>(A + arow * 128 + kk * 32 + g * 8);
    } else if constexpr (ASRC == 2) {
        const float* A = (const float*)Ain;
        #pragma unroll
        for (int kk = 0; kk < 4; ++kk) {
            const int ch0 = kk * 32 + g * 8;
            const f32x4* src = reinterpret_cast<const f32x4*>(A + arow * 128 + ch0);
            f32x4 v0 = src[0], v1 = src[1];
            short8 v;
            #pragma unroll
            for (int i = 0; i < 4; ++i) {
                v[i]     = (short)f2bf(fmaxf(fmaf(asc[ch0 + i],     v0[i], ash[ch0 + i]),     0.f));
                v[4 + i] = (short)f2bf(fmaxf(fmaf(asc[ch0 + 4 + i], v1[i], ash[ch0 + 4 + i]), 0.f));
            }
            afr[kk] = v;
        }
    } else {
        const unsigned short* A = (const unsigned short*)Ain;
        #pragma unroll
        for (int kk = 0; kk < 4; ++kk) {
            const int ch0 = kk * 32 + g * 8;
            short8 raw = *reinterpret_cast<const short8*>(A + arow * 128 + ch0);
            short8 v;
            #pragma unroll
            for (int i = 0; i < 8; ++i) {
                float x = fmaxf(fmaf(asc[ch0 + i], bf2f((unsigned short)raw[i]), ash[ch0 + i]), 0.f);
                v[i] = (short)f2bf(x);
            }
            afr[kk] = v;
        }
    }
    f32x4 acc[8];
    #pragma unroll
    for (int n = 0; n < 8; ++n) acc[n] = f32x4{0.f, 0.f, 0.f, 0.f};
    #pragma unroll
    for (int kk = 0; kk < 4; ++kk) {
        const int fb = (kk * 4 + g) * 1024 + l16 * 8;
        #pragma unroll
        for (int n = 0; n < 8; ++n) {
            short8 bf = *reinterpret_cast<const short8*>(&bl[fb + n * 128]);
            acc[n] = __builtin_amdgcn_mfma_f32_16x16x32_bf16(afr[kk], bf, acc[n], 0, 0, 0);
        }
    }
    const long orow0 = (long)blockIdx.x * 64 + wid * 16 + g * 4;
    float bia[8];
    if constexpr (BIAS) {
        #pragma unroll
        for (int n = 0; n < 8; ++n) bia[n] = Bias[n * 16 + l16];
    }
    float lsf[8], lqf[8];
    #pragma unroll
    for (int n = 0; n < 8; ++n) { lsf[n] = 0.f; lqf[n] = 0.f; }
    #pragma unroll
    for (int n = 0; n < 8; ++n) {
        #pragma unroll
        for (int r = 0; r < 4; ++r) {
            float v = acc[n][r];
            if constexpr (BIAS) v += bia[n];
            if constexpr (STATS) { lsf[n] += v; lqf[n] += v * v; }
            Out[(orow0 + r) * 128 + n * 16 + l16] = f2bf(v);
        }
    }
    if constexpr (STATS) {
        const int slot = blockIdx.x & (NSLOT - 1);
        #pragma unroll
        for (int n = 0; n < 8; ++n) {
            float s = lsf[n], q = lqf[n];
            s += __shfl_xor(s, 16); s += __shfl_xor(s, 32);
            q += __shfl_xor(q, 16); q += __shfl_xor(q, 32);
            if (g == 0) {
                atomicAdd(&dsum[slot * 128 + n * 16 + l16], (double)s);
                atomicAdd(&dsq[slot * 128 + n * 16 + l16], (double)q);
            }
        }
        bn_finalize_block(dsum, dsq, bng, bnb, oscale, oshift, 128, (double)NPOINTS, ctr, nblk, &lastf);
    }
}

// fused q/k/v: 3 GEMMs sharing one A pass; bn1+relu fused into A load.
__global__ __launch_bounds__(512) void k_qkv3(
    const unsigned short* __restrict__ Y,
    const float* __restrict__ sc, const float* __restrict__ sh,
    const float* __restrict__ Wq, const float* __restrict__ Bq,
    const float* __restrict__ Wk, const float* __restrict__ Bk,
    const float* __restrict__ Wv, const float* __restrict__ Bv,
    unsigned short* __restrict__ Qo, unsigned short* __restrict__ Ko,
    unsigned short* __restrict__ Vo)
{
    __shared__ unsigned short bl[3 * 16384];   // 96 KB
    const int tid = threadIdx.x;
    #pragma unroll
    for (int m = 0; m < 3; ++m) {
        const float* W = (m == 0) ? Wq : (m == 1) ? Wk : Wv;
        for (int e = tid; e < 16384; e += 512) {
            int k = e >> 7, n = e & 127;
            int f = ((k >> 5) << 2) | ((k >> 3) & 3);
            bl[m * 16384 + f * 1024 + (n >> 4) * 128 + (n & 15) * 8 + (k & 7)] = f2bf(W[e]);
        }
    }
    __syncthreads();
    const int wid = tid >> 6, lane = tid & 63;
    const int l16 = lane & 15, g = lane >> 4;
    const long arow = (long)blockIdx.x * 128 + wid * 16 + l16;
    short8 afr[4];
    #pragma unroll
    for (int kk = 0; kk < 4; ++kk) {
        const int ch0 = kk * 32 + g * 8;
        short8 raw = *reinterpret_cast<const short8*>(Y + arow * 128 + ch0);
        short8 v;
        #pragma unroll
        for (int i = 0; i < 8; ++i) {
            float x = fmaxf(fmaf(sc[ch0 + i], bf2f((unsigned short)raw[i]), sh[ch0 + i]), 0.f);
            v[i] = (short)f2bf(x);
        }
        afr[kk] = v;
    }
    const long orow0 = (long)blockIdx.x * 128 + wid * 16 + g * 4;
    #pragma unroll
    for (int m = 0; m < 3; ++m) {
        const float* Bias = (m == 0) ? Bq : (m == 1) ? Bk : Bv;
        unsigned short* Out = (m == 0) ? Qo : (m == 1) ? Ko : Vo;
        f32x4 acc[8];
        #pragma unroll
        for (int n = 0; n < 8; ++n) acc[n] = f32x4{0.f, 0.f, 0.f, 0.f};
        #pragma unroll
        for (int kk = 0; kk < 4; ++kk) {
            const int fb = m * 16384 + (kk * 4 + g) * 1024 + l16 * 8;
            #pragma unroll
            for (int n = 0; n < 8; ++n) {
                short8 bf = *reinterpret_cast<const short8*>(&bl[fb + n * 128]);
                acc[n] = __builtin_amdgcn_mfma_f32_16x16x32_bf16(afr[kk], bf, acc[n], 0, 0, 0);
            }
        }
        #pragma unroll
        for (int n = 0; n < 8; ++n) {
            const float bia = Bias[n * 16 + l16];
            #pragma unroll
            for (int r = 0; r < 4; ++r)
                Out[(orow0 + r) * 128 + n * 16 + l16] = f2bf(acc[n][r] + bia);
        }
    }
}

// stats of h = rel @ fd_w1 + fd_b1 over (B,N,K), 3 channels (+finalize)
__global__ __launch_bounds__(256) void k_fd_stats(
    const float* __restrict__ xyz, const int* __restrict__ knn,
    const float* __restrict__ fdw1, const float* __restrict__ fdb1,
    double* __restrict__ dsum, double* __restrict__ dsq,
    const float* __restrict__ bng, const float* __restrict__ bnb,
    float* __restrict__ oscale, float* __restrict__ oshift,
    unsigned int* __restrict__ ctr, unsigned int nblk)
{
    __shared__ unsigned int lastf;
    float wd[9], bd[3];
    #pragma unroll
    for (int i = 0; i < 9; ++i) wd[i] = fdw1[i];
    #pragma unroll
    for (int j = 0; j < 3; ++j) bd[j] = fdb1[j];
    double ls[3] = {0, 0, 0}, lq[3] = {0, 0, 0};
    for (int s = blockIdx.x * blockDim.x + threadIdx.x; s < NSAMP; s += gridDim.x * blockDim.x) {
        int p = s >> 4;
        int b = p >> 14, n = p & 16383;
        int idx = knn[s];
        const float* pa = xyz + (b * 16384 + n) * 3;
        const float* pb = xyz + (b * 16384 + idx) * 3;
        float r0 = pa[0] - pb[0], r1 = pa[1] - pb[1], r2 = pa[2] - pb[2];
        #pragma unroll
        for (int j = 0; j < 3; ++j) {
            float h = r0 * wd[j] + r1 * wd[3 + j] + r2 * wd[6 + j] + bd[j];
            ls[j] += h; lq[j] += (double)h * h;
        }
    }
    const int slot = blockIdx.x & (NSLOT - 1);
    #pragma unroll
    for (int j = 0; j < 3; ++j) {
        double v = ls[j];
        for (int o = 32; o; o >>= 1) v += __shfl_down(v, o);
        if ((threadIdx.x & 63) == 0) atomicAdd(&dsum[slot * 3 + j], v);
        v = lq[j];
        for (int o = 32; o; o >>= 1) v += __shfl_down(v, o);
        if ((threadIdx.x & 63) == 0) atomicAdd(&dsq[slot * 3 + j], v);
    }
    bn_finalize_block(dsum, dsq, bng, bnb, oscale, oshift, 3, (double)NSAMP, ctr, nblk, &lastf);
}

// stats of attn0 = q - k_gather + pos_enc, 128 ch (+finalize). Barrier-free sweeps.
__global__ __launch_bounds__(256) void k_attn1_stats(
    const unsigned short* __restrict__ Q, const unsigned short* __restrict__ Kb,
    const float* __restrict__ xyz, const int* __restrict__ knn,
    const float* __restrict__ fdw1, const float* __restrict__ fdb1,
    const float* __restrict__ fds, const float* __restrict__ fdh,
    const float* __restrict__ fdw2, const float* __restrict__ fdb2,
    double* __restrict__ dsum, double* __restrict__ dsq,
    const float* __restrict__ bng, const float* __restrict__ bnb,
    float* __restrict__ oscale, float* __restrict__ oshift,
    unsigned int* __restrict__ ctr, unsigned int nblk)
{
    __shared__ float pe3_all[4][16][4];
    __shared__ double red[1024];
    __shared__ unsigned int lastf;
    const int tid = threadIdx.x, w = tid >> 6, l = tid & 63;
    float (*pe3)[4] = pe3_all[w];
    const int c0 = 2 * l;
    const float w0a = fdw2[c0],       w0b = fdw2[c0 + 1];
    const float w1a = fdw2[128 + c0], w1b = fdw2[129 + c0];
    const float w2a = fdw2[256 + c0], w2b = fdw2[257 + c0];
    const float bba = fdb2[c0],       bbb = fdb2[c0 + 1];
    float wd[9], bd[3], fs3[3], fh3[3];
    #pragma unroll
    for (int i = 0; i < 9; ++i) wd[i] = fdw1[i];
    #pragma unroll
    for (int j = 0; j < 3; ++j) { bd[j] = fdb1[j]; fs3[j] = fds[j]; fh3[j] = fdh[j]; }
    PIN_DECODE(blockIdx.x);
    const unsigned* kb32 = (const unsigned*)(Kb + (((size_t)batch) << 14) * 128);
    double ls0 = 0, lq0 = 0, ls1 = 0, lq1 = 0;
    for (int s = 0; s < 4; ++s) {
        const int p = PIN_POINT(s, w);
        LOAD_IDX(idx, p);
        if (l < 16) {
            const int mi = knn[p * 16 + l];
            const int n = p & 16383;
            const float* pa = xyz + (batch * 16384 + n) * 3;
            const float* pb = xyz + (batch * 16384 + mi) * 3;
            const float r0 = pa[0] - pb[0], r1 = pa[1] - pb[1], r2 = pa[2] - pb[2];
            #pragma unroll
            for (int j = 0; j < 3; ++j) {
                float h = r0 * wd[j] + r1 * wd[3 + j] + r2 * wd[6 + j] + bd[j];
                pe3[l][j] = fmaxf(fmaf(fs3[j], h, fh3[j]), 0.f);
            }
        }
        unsigned kw[16];
        #pragma unroll
        for (int kk = 0; kk < 16; ++kk) kw[kk] = kb32[idx[kk] * 64 + l];
        const unsigned qw = ((const unsigned*)(Q + (size_t)p * 128))[l];
        const float qa = bflo(qw), qb = bfhi(qw);
        float pls0 = 0.f, plq0 = 0.f, pls1 = 0.f, plq1 = 0.f;
        #pragma unroll
        for (int kk = 0; kk < 16; ++kk) {
            const float pea = fmaf(pe3[kk][0], w0a, fmaf(pe3[kk][1], w1a, fmaf(pe3[kk][2], w2a, bba)));
            const float peb = fmaf(pe3[kk][0], w0b, fmaf(pe3[kk][1], w1b, fmaf(pe3[kk][2], w2b, bbb)));
            const float a0 = qa - bflo(kw[kk]) + pea;
            const float a1 = qb - bfhi(kw[kk]) + peb;
            pls0 += a0; plq0 = fmaf(a0, a0, plq0);
            pls1 += a1; plq1 = fmaf(a1, a1, plq1);
        }
        ls0 += pls0; lq0 += plq0; ls1 += pls1; lq1 += plq1;
    }
    red[tid] = ls0; red[256 + tid] = ls1; red[512 + tid] = lq0; red[768 + tid] = lq1;
    __syncthreads();
    if (w == 0) {
        const int slot = blockIdx.x & (NSLOT - 1);
        const double s0 = red[l] + red[64 + l] + red[128 + l] + red[192 + l];
        const double s1 = red[256 + l] + red[320 + l] + red[384 + l] + red[448 + l];
        const double q0 = red[512 + l] + red[576 + l] + red[640 + l] + red[704 + l];
        const double q1 = red[768 + l] + red[832 + l] + red[896 + l] + red[960 + l];
        atomicAdd(&dsum[slot * 128 + c0], s0); atomicAdd(&dsum[slot * 128 + c0 + 1], s1);
        atomicAdd(&dsq[slot * 128 + c0], q0); atomicAdd(&dsq[slot * 128 + c0 + 1], q1);
    }
    bn_finalize_block(dsum, dsq, bng, bnb, oscale, oshift, 128, (double)NSAMP, ctr, nblk, &lastf);
}

// stats of t = relu(bn(attn0)) @ fg_w1 + fg_b1, 16 ch (+finalize); stores t bf16.
__global__ __launch_bounds__(256) void k_attn2_stats(
    const unsigned short* __restrict__ Q, const unsigned short* __restrict__ Kb,
    const float* __restrict__ xyz, const int* __restrict__ knn,
    const float* __restrict__ fdw1, const float* __restrict__ fdb1,
    const float* __restrict__ fds, const float* __restrict__ fdh,
    const float* __restrict__ fdw2, const float* __restrict__ fdb2,
    const float* __restrict__ g1s, const float* __restrict__ g1h,
    const float* __restrict__ fgw1, const float* __restrict__ fgb1,
    unsigned short* __restrict__ Tb,
    double* __restrict__ dsum, double* __restrict__ dsq,
    const float* __restrict__ bng, const float* __restrict__ bnb,
    float* __restrict__ oscale, float* __restrict__ oshift,
    unsigned int* __restrict__ ctr, unsigned int nblk)
{
    __shared__ __align__(16) unsigned short s1b_all[4][2048];
    __shared__ float pe3_all[4][16][4];
    __shared__ unsigned int lastf;
    const int tid = threadIdx.x, w = tid >> 6, l = tid & 63;
    unsigned short* s1b = s1b_all[w];
    float (*pe3)[4] = pe3_all[w];
    const int c0 = 2 * l;
    const int a16 = l & 15, g8 = (l >> 4) * 8;
    const float w0a = fdw2[c0],       w0b = fdw2[c0 + 1];
    const float w1a = fdw2[128 + c0], w1b = fdw2[129 + c0];
    const float w2a = fdw2[256 + c0], w2b = fdw2[257 + c0];
    const float bba = fdb2[c0],       bbb = fdb2[c0 + 1];
    const float sA = g1s[c0], hA = g1h[c0];
    const float sB = g1s[c0 + 1], hB = g1h[c0 + 1];
    const float tb = fgb1[a16];
    float wd[9], bd[3], fs3[3], fh3[3];
    #pragma unroll
    for (int i = 0; i < 9; ++i) wd[i] = fdw1[i];
    #pragma unroll
    for (int j = 0; j < 3; ++j) { bd[j] = fdb1[j]; fs3[j] = fds[j]; fh3[j] = fdh[j]; }
    short8 bfrag[4];
    #pragma unroll
    for (int s = 0; s < 4; ++s)
        #pragma unroll
        for (int i = 0; i < 8; ++i)
            bfrag[s][i] = (short)f2bf(fgw1[(32 * s + g8 + i) * 16 + a16]);
    PIN_DECODE(blockIdx.x);
    const unsigned* kb32 = (const unsigned*)(Kb + (((size_t)batch) << 14) * 128);
    double ls = 0.0, lq = 0.0;
    for (int s = 0; s < 4; ++s) {
        const int p = PIN_POINT(s, w);
        LOAD_IDX(idx, p);
        if (l < 16) {
            const int mi = knn[p * 16 + l];
            const int n = p & 16383;
            const float* pa = xyz + (batch * 16384 + n) * 3;
            const float* pb = xyz + (batch * 16384 + mi) * 3;
            const float r0 = pa[0] - pb[0], r1 = pa[1] - pb[1], r2 = pa[2] - pb[2];
            #pragma unroll
            for (int j = 0; j < 3; ++j) {
                float h = r0 * wd[j] + r1 * wd[3 + j] + r2 * wd[6 + j] + bd[j];
                pe3[l][j] = fmaxf(fmaf(fs3[j], h, fh3[j]), 0.f);
            }
        }
        unsigned kw[16];
        #pragma unroll
        for (int kk = 0; kk < 16; ++kk) kw[kk] = kb32[idx[kk] * 64 + l];
        const unsigned qw = ((const unsigned*)(Q + (size_t)p * 128))[l];
        const float qa = bflo(qw), qb = bfhi(qw);
        #pragma unroll
        for (int kk = 0; kk < 16; ++kk) {
            const float pea = fmaf(pe3[kk][0], w0a, fmaf(pe3[kk][1], w1a, fmaf(pe3[kk][2], w2a, bba)));
            const float peb = fmaf(pe3[kk][0], w0b, fmaf(pe3[kk][1], w1b, fmaf(pe3[kk][2], w2b, bbb)));
            const float a0 = qa - bflo(kw[kk]) + pea;
            const float a1 = qb - bfhi(kw[kk]) + peb;
            const float v0 = fmaxf(fmaf(sA, a0, hA), 0.f);
            const float v1 = fmaxf(fmaf(sB, a1, hB), 0.f);
            ((unsigned*)s1b)[(((kk * 128 + c0) ^ ((kk & 7) << 3)) >> 1)] = pack2bf(v0, v1);
        }
        f32x4 acc = {0.f, 0.f, 0.f, 0.f};
        #pragma unroll
        for (int ss = 0; ss < 4; ++ss) {
            const int ai = (a16 * 128 + ss * 32 + g8) ^ ((a16 & 7) << 3);
            short8 af = *reinterpret_cast<const short8*>(&s1b[ai]);
            acc = __builtin_amdgcn_mfma_f32_16x16x32_bf16(af, bfrag[ss], acc, 0, 0, 0);
        }
        short4v tq;
        float pls = 0.f, plq = 0.f;
        #pragma unroll
        for (int r = 0; r < 4; ++r) {
            const float t = acc[r] + tb;
            tq[r] = (short)f2bf(t);
            pls += t; plq = fmaf(t, t, plq);
        }
        *reinterpret_cast<short4v*>(Tb + (size_t)p * 256 + l * 4) = tq;
        ls += pls; lq += plq;
    }
    __syncthreads();   // all waves done with s1b before red aliases it
    double* red = (double*)&s1b_all[0][0];
    red[tid] = ls; red[256 + tid] = lq;
    __syncthreads();
    if (tid < 16) {
        const int slot = blockIdx.x & (NSLOT - 1);
        double s = 0.0, q = 0.0;
        for (int i = 0; i < 16; ++i) { s += red[tid + 16 * i]; q += red[256 + tid + 16 * i]; }
        atomicAdd(&dsum[slot * 16 + tid], s); atomicAdd(&dsq[slot * 16 + tid], q);
    }
    bn_finalize_block(dsum, dsq, bng, bnb, oscale, oshift, 16, (double)NSAMP, ctr, nblk, &lastf);
}

// final attention from stored t: bn2 -> stage2 -> softmax -> PV ; bn2 stats. RES bf16.
__global__ __launch_bounds__(256) void k_attn_final(
    const unsigned short* __restrict__ Tb, const unsigned short* __restrict__ Vb,
    const float* __restrict__ xyz, const int* __restrict__ knn,
    const float* __restrict__ fdw1, const float* __restrict__ fdb1,
    const float* __restrict__ fds, const float* __restrict__ fdh,
    const float* __restrict__ fdw2, const float* __restrict__ fdb2,
    const float* __restrict__ g2s, const float* __restrict__ g2h,
    const float* __restrict__ fgw2, const float* __restrict__ fgb2,
    unsigned short* __restrict__ Res, double* __restrict__ dsum, double* __restrict__ dsq,
    const float* __restrict__ bng, const float* __restrict__ bnb,
    float* __restrict__ oscale, float* __restrict__ oshift,
    unsigned int* __restrict__ ctr, unsigned int nblk)
{
    __shared__ float t2l_all[4][272];
    __shared__ float wl_all[4][272];
    __shared__ float pe3_all[4][16][4];
    __shared__ double red[1024];
    __shared__ unsigned int lastf;
    const int tid = threadIdx.x, w = tid >> 6, l = tid & 63;
    float* t2l = t2l_all[w];
    float* wl  = wl_all[w];
    float (*pe3)[4] = pe3_all[w];
    const int c0 = 2 * l;
    const int a16 = l & 15, g4 = l >> 4;
    const int aA = c0 & 15;
    const float w0a = fdw2[c0],       w0b = fdw2[c0 + 1];
    const float w1a = fdw2[128 + c0], w1b = fdw2[129 + c0];
    const float w2a = fdw2[256 + c0], w2b = fdw2[257 + c0];
    const float bba = fdb2[c0],       bbb = fdb2[c0 + 1];
    const float s2a = g2s[a16], s2h = g2h[a16], b2a = fgb2[a16];
    float wd[9], bd[3], fs3[3], fh3[3];
    #pragma unroll
    for (int i = 0; i < 9; ++i) wd[i] = fdw1[i];
    #pragma unroll
    for (int j = 0; j < 3; ++j) { bd[j] = fdb1[j]; fs3[j] = fds[j]; fh3[j] = fdh[j]; }
    float wv2[16];
    #pragma unroll
    for (int j = 0; j < 16; ++j) wv2[j] = fgw2[j * 16 + a16];
    PIN_DECODE(blockIdx.x);
    const unsigned* vb32 = (const unsigned*)(Vb + (((size_t)batch) << 14) * 128);
    double lsA = 0.0, lqA = 0.0, lsB = 0.0, lqB = 0.0;
    for (int s = 0; s < 4; ++s) {
        const int p = PIN_POINT(s, w);
        LOAD_IDX(idx, p);
        unsigned vw[16];
        #pragma unroll
        for (int kk = 0; kk < 16; ++kk) vw[kk] = vb32[idx[kk] * 64 + l];
        if (l < 16) {
            const int mi = knn[p * 16 + l];
            const int n = p & 16383;
            const float* pa = xyz + (batch * 16384 + n) * 3;
            const float* pb = xyz + (batch * 16384 + mi) * 3;
            const float r0 = pa[0] - pb[0], r1 = pa[1] - pb[1], r2 = pa[2] - pb[2];
            #pragma unroll
            for (int j = 0; j < 3; ++j) {
                float h = r0 * wd[j] + r1 * wd[3 + j] + r2 * wd[6 + j] + bd[j];
                pe3[l][j] = fmaxf(fmaf(fs3[j], h, fh3[j]), 0.f);
            }
        }
        short4v tv = *reinterpret_cast<const short4v*>(Tb + (size_t)p * 256 + l * 4);
        #pragma unroll
        for (int r = 0; r < 4; ++r)
            t2l[(g4 * 4 + r) * 17 + a16] = fmaxf(fmaf(s2a, bf2f((unsigned short)tv[r]), s2h), 0.f);
        float ur[4];
        #pragma unroll
        for (int r = 0; r < 4; ++r) {
            float u = b2a;
            #pragma unroll
            for (int j = 0; j < 16; ++j) u = fmaf(t2l[(g4 * 4 + r) * 17 + j], wv2[j], u);
            ur[r] = u;
        }
        float m = fmaxf(fmaxf(ur[0], ur[1]), fmaxf(ur[2], ur[3]));
        m = fmaxf(m, __shfl_xor(m, 16));
        m = fmaxf(m, __shfl_xor(m, 32));
        const float e0 = __expf(ur[0] - m), e1 = __expf(ur[1] - m);
        const float e2 = __expf(ur[2] - m), e3 = __expf(ur[3] - m);
        float ss = e0 + e1 + e2 + e3;
        ss += __shfl_xor(ss, 16);
        ss += __shfl_xor(ss, 32);
        const float inv = 1.f / ss;
        wl[(g4 * 4 + 0) * 17 + a16] = e0 * inv;
        wl[(g4 * 4 + 1) * 17 + a16] = e1 * inv;
        wl[(g4 * 4 + 2) * 17 + a16] = e2 * inv;
        wl[(g4 * 4 + 3) * 17 + a16] = e3 * inv;
        float rc0 = 0.f, rc1 = 0.f;
        #pragma unroll
        for (int kk = 0; kk < 16; ++kk) {
            const float wgtA = wl[kk * 17 + aA];
            const float wgtB = wl[kk * 17 + aA + 1];
            const float pea = fmaf(pe3[kk][0], w0a, fmaf(pe3[kk][1], w1a, fmaf(pe3[kk][2], w2a, bba)));
            const float peb = fmaf(pe3[kk][0], w0b, fmaf(pe3[kk][1], w1b, fmaf(pe3[kk][2], w2b, bbb)));
            rc0 = fmaf(bflo(vw[kk]) + pea, wgtA, rc0);
            rc1 = fmaf(bfhi(vw[kk]) + peb, wgtB, rc1);
        }
        ((unsigned*)Res)[(size_t)p * 64 + l] = pack2bf(rc0, rc1);
        lsA += rc0; lqA += (double)rc0 * rc0;
        lsB += rc1; lqB += (double)rc1 * rc1;
    }
    red[tid] = lsA; red[256 + tid] = lsB; red[512 + tid] = lqA; red[768 + tid] = lqB;
    __syncthreads();
    if (w == 0) {
        const int slot = blockIdx.x & (NSLOT - 1);
        const double s0 = red[l] + red[64 + l] + red[128 + l] + red[192 + l];
        const double s1 = red[256 + l] + red[320 + l] + red[384 + l] + red[448 + l];
        const double q0 = red[512 + l] + red[576 + l] + red[640 + l] + red[704 + l];
        const double q1 = red[768 + l] + red[832 + l] + red[896 + l] + red[960 + l];
        atomicAdd(&dsum[slot * 128 + c0], s0); atomicAdd(&dsum[slot * 128 + c0 + 1], s1);
        atomicAdd(&dsq[slot * 128 + c0], q0); atomicAdd(&dsq[slot * 128 + c0 + 1], q1);
    }
    bn_finalize_block(dsum, dsq, bng, bnb, oscale, oshift, 128, (double)NPOINTS, ctr, nblk, &lastf);
}

// out = relu(bn3(y3) + identity); tail blocks copy xyz -> out[0:98304)
__global__ __launch_bounds__(256) void k_out(
    const unsigned short* __restrict__ Y3, const float* __restrict__ sc,
    const float* __restrict__ sh, const float* __restrict__ feat,
    const float* __restrict__ xyz, float* __restrict__ out)
{
    if (blockIdx.x < 2048) {
        const int v = blockIdx.x * 256 + threadIdx.x;
        const int base = v * 8;
        short8 y = *reinterpret_cast<const short8*>(&Y3[base]);
        const int c0 = base & 127;
        float* o = out + 98304;
        #pragma unroll
        for (int j = 0; j < 8; ++j) {
            float val = fmaf(sc[c0 + j], bf2f((unsigned short)y[j]), sh[c0 + j]) + feat[base + j];
            o[base + j] = fmaxf(val, 0.f);
        }
    } else {
        const int v = (blockIdx.x - 2048) * 256 + threadIdx.x;
        const int base = v * 8;     // 48 blocks * 256 thr * 8 = 98304
        const f32x4* src = reinterpret_cast<const f32x4*>(xyz + base);
        f32x4* dst = reinterpret_cast<f32x4*>(out + base);
        dst[0] = src[0];
        dst[1] = src[1];
    }
}

extern "C" void kernel_launch(void* const* d_in, const int* in_sizes, int n_in,
                              void* d_out, int out_size, void* d_ws, size_t ws_size,
                              hipStream_t stream)
{
    (void)in_sizes; (void)n_in; (void)out_size; (void)ws_size;
    const float* xyz   = (const float*)d_in[0];
    const float* feat  = (const float*)d_in[1];
    const int*   knn   = (const int*)d_in[2];
    const float* w1    = (const float*)d_in[3];
    const float* bn1g  = (const float*)d_in[4];
    const float* bn1b  = (const float*)d_in[5];
    const float* lqw   = (const float*)d_in[6];
    const float* lqb   = (const float*)d_in[7];
    const float* lkw   = (const float*)d_in[8];
    const float* lkb   = (const float*)d_in[9];
    const float* lvw   = (const float*)d_in[10];
    const float* lvb   = (const float*)d_in[11];
    const float* fdw1  = (const float*)d_in[12];
    const float* fdb1  = (const float*)d_in[13];
    const float* fdbng = (const float*)d_in[14];
    const float* fdbnb = (const float*)d_in[15];
    const float* fdw2  = (const float*)d_in[16];
    const float* fdb2  = (const float*)d_in[17];
    const float* g1g   = (const float*)d_in[18];
    const float* g1b   = (const float*)d_in[19];
    const float* fgw1  = (const float*)d_in[20];
    const float* fgb1  = (const float*)d_in[21];
    const float* g2g   = (const float*)d_in[22];
    const float* g2b   = (const float*)d_in[23];
    const float* fgw2  = (const float*)d_in[24];
    const float* fgb2  = (const float*)d_in[25];
    const float* bn2g  = (const float*)d_in[26];
    const float* bn2b  = (const float*)d_in[27];
    const float* w3    = (const float*)d_in[28];
    const float* bn3g  = (const float*)d_in[29];
    const float* bn3b  = (const float*)d_in[30];

    unsigned short* YBF = (unsigned short*)d_ws;            // bf16 y   [0,8M)
    unsigned short* RES = YBF;                              // bf16 res overlays y [0,8M)
    unsigned short* Qb  = YBF + 2 * 4194304;                // [16M,24M)
    unsigned short* Kb  = Qb + 4194304;                     // [24M,32M)
    unsigned short* Vb  = Kb + 4194304;                     // [32M,40M)
    unsigned short* Tb  = Vb + 4194304;                     // [40M,56M) stored t (bf16)
    unsigned short* Y3  = Qb;                               // overlays Q
    double* ds = (double*)(Tb + 8388608);
    unsigned int* ctrs = (unsigned int*)(ds + O_END);       // 6 counters
    float* fs = (float*)(ds + O_END + 8);

    hipMemsetAsync(ds, 0, (size_t)(O_END + 8) * sizeof(double), stream);

    // bn1 over feat@w1 (stats+finalize folded)
    k_mgemm<0, true, false><<<512, 256, 0, stream>>>(feat, w1, nullptr, YBF, nullptr, nullptr,
                                                     ds + O_BN1S, ds + O_BN1Q,
                                                     bn1g, bn1b, fs + 0, fs + 128, ctrs + 0, 512u);
    // fused q,k,v projections (bn1+relu folded into A load)
    k_qkv3<<<256, 512, 0, stream>>>(YBF, fs + 0, fs + 128, lqw, lqb, lkw, lkb, lvw, lvb, Qb, Kb, Vb);
    // fd BN stats (3ch)
    k_fd_stats<<<256, 256, 0, stream>>>(xyz, knn, fdw1, fdb1, ds + O_FDS, ds + O_FDQ,
                                        fdbng, fdbnb, fs + 256, fs + 264, ctrs + 1, 256u);
    // fg_bn1 stats (128ch)
    k_attn1_stats<<<2048, 256, 0, stream>>>(Qb, Kb, xyz, knn, fdw1, fdb1, fs + 256, fs + 264,
                                            fdw2, fdb2, ds + O_G1S, ds + O_G1Q,
                                            g1g, g1b, fs + 272, fs + 400, ctrs + 2, 2048u);
    // fg_bn2 stats (16ch) + store t
    k_attn2_stats<<<2048, 256, 0, stream>>>(Qb, Kb, xyz, knn, fdw1, fdb1, fs + 256, fs + 264,
                                            fdw2, fdb2, fs + 272, fs + 400, fgw1, fgb1, Tb,
                                            ds + O_G2S, ds + O_G2Q,
                                            g2g, g2b, fs + 528, fs + 544, ctrs + 3, 2048u);
    // final attention from stored t -> RES (bf16), bn2 stats
    k_attn_final<<<2048, 256, 0, stream>>>(Tb, Vb, xyz, knn, fdw1, fdb1, fs + 256, fs + 264,
                                           fdw2, fdb2, fs + 528, fs + 544, fgw2, fgb2,
                                           RES, ds + O_BN2S, ds + O_BN2Q,
                                           bn2g, bn2b, fs + 560, fs + 688, ctrs + 4, 2048u);
    // y3 = relu(bn2(res)) @ w3 (bn2+relu folded, bf16 A), bn3 stats
    k_mgemm<3, true, false><<<512, 256, 0, stream>>>(RES, w3, nullptr, Y3, fs + 560, fs + 688,
                                                     ds + O_BN3S, ds + O_BN3Q,
                                                     bn3g, bn3b, fs + 816, fs + 944, ctrs + 5, 512u);
    // output (+ xyz copy in tail blocks)
    float* outp = (float*)d_out;
    k_out<<<2096, 256, 0, stream>>>(Y3, fs + 816, fs + 944, feat, xyz, outp);
}